// Round 2
// 521.205 us; speedup vs baseline: 1.0876x; 1.0876x over previous
//
#include <hip/hip_runtime.h>
#include <hip/hip_bf16.h>
#include <stdint.h>

// GCNAE: N nodes, E edges, IN features, H hidden.
// Inputs fp32 (bf16-rounded values). Output fp32: adj [N,N] then z [N,H].
#define N_NODES 10000
#define N_EDGES 320000
#define DIM_IN  128
#define DIM_H   64
#define SSTR    72     // LDS row stride in shorts (64 + 8 pad -> 2-way banks only)
#define CSTR    132    // fp32 epilogue LDS stride (128 + 4 pad -> 2-way banks)

typedef __attribute__((ext_vector_type(8))) short  short8;   // 8 bf16 (MFMA A/B frag)
typedef __attribute__((ext_vector_type(4))) float  f32x4;    // MFMA C/D frag + stores

__device__ __forceinline__ unsigned short f2bf(float f) {
    union { float f; unsigned int i; } v; v.f = f;
    unsigned int u = v.i;
    return (unsigned short)((u + 0x7fffu + ((u >> 16) & 1u)) >> 16);  // RNE
}

// ---- 1. histogram of in-degrees -------------------------------------------
__global__ void hist_kernel(const int* __restrict__ ei, int* __restrict__ deg) {
    int e = blockIdx.x * blockDim.x + threadIdx.x;
    if (e < N_EDGES) atomicAdd(&deg[ei[N_EDGES + e]], 1);   // row 1 = dst
}

// ---- 2. exclusive scan (single block, 1024 threads, 10 elems/thread) ------
__global__ void __launch_bounds__(1024) scan_kernel(const int* __restrict__ deg,
                                                    int* __restrict__ offs,
                                                    int* __restrict__ cursor) {
    __shared__ int part[1024];
    int t = threadIdx.x;
    int base = t * 10;
    int local[10];
    int s = 0;
    for (int i = 0; i < 10; ++i) {
        int idx = base + i;
        int d = (idx < N_NODES) ? deg[idx] : 0;
        local[i] = d; s += d;
    }
    part[t] = s;
    __syncthreads();
    for (int o = 1; o < 1024; o <<= 1) {
        int add = (t >= o) ? part[t - o] : 0;
        __syncthreads();
        part[t] += add;
        __syncthreads();
    }
    int run = part[t] - s;
    for (int i = 0; i < 10; ++i) {
        int idx = base + i;
        if (idx < N_NODES) { offs[idx] = run; cursor[idx] = run; run += local[i]; }
    }
    if (t == 1023) offs[N_NODES] = part[1023];
}

// ---- 3. bucket edge ids into CSR ------------------------------------------
__global__ void bucket_kernel(const int* __restrict__ ei, int* __restrict__ cursor,
                              int* __restrict__ esorted) {
    int e = blockIdx.x * blockDim.x + threadIdx.x;
    if (e < N_EDGES) {
        int d = ei[N_EDGES + e];
        int slot = atomicAdd(&cursor[d], 1);
        esorted[slot] = e;
    }
}

// ---- 4. per-node aggregate + fused dense: z = agg@W_rel + x@W_root + b ----
__global__ void __launch_bounds__(64) agg_dense_kernel(
    const float* __restrict__ x,
    const int* __restrict__ ei,
    const float* __restrict__ ew,
    const float* __restrict__ wrel,
    const float* __restrict__ wroot,
    const float* __restrict__ bias,
    const int* __restrict__ offs,
    const int* __restrict__ esorted,
    float* __restrict__ out)               // d_out (fp32)
{
    int i = blockIdx.x;
    int lane = threadIdx.x;
    __shared__ float aggL[DIM_IN];
    __shared__ float xL[DIM_IN];

    int beg = offs[i], end = offs[i + 1];
    const float2* xrow_i = (const float2*)(x + (size_t)i * DIM_IN);
    float2 xi = xrow_i[lane];
    float a0 = 0.f, a1 = 0.f;
    for (int p = beg; p < end; ++p) {
        int e = esorted[p];
        int s = ei[e];                     // row 0 = src
        float w = ew[e];
        float2 xv = ((const float2*)(x + (size_t)s * DIM_IN))[lane];
        a0 += w * xv.x;
        a1 += w * xv.y;
    }
    aggL[2 * lane]     = a0;
    aggL[2 * lane + 1] = a1;
    xL[2 * lane]       = xi.x;
    xL[2 * lane + 1]   = xi.y;
    __syncthreads();

    int h = lane;
    float acc = bias[h];
    for (int k = 0; k < DIM_IN; ++k) {
        acc += aggL[k] * wrel[k * DIM_H + h];
        acc += xL[k]   * wroot[k * DIM_H + h];
    }
    out[(size_t)N_NODES * N_NODES + (size_t)i * DIM_H + h] = acc;  // fp32 z
}

// ---- 5. adj = sigmoid(z @ z^T) --------------------------------------------
// Block tile 128x128, 4 waves of 64x64. z panels staged fp32->bf16 via LDS.
// Store-path rework (R0/R1):
//  - blockIdx.x walks COLUMN tiles: consecutive blocks cooperatively fill
//    contiguous 128-row bands (DRAM/L2 write locality; old order scattered
//    ~1024 resident blocks over row-strided fragments of the whole surface).
//  - Epilogue transposes acc through LDS (reusing the sA/sB staging buffer,
//    zero extra LDS -> occupancy unchanged) so stores become nontemporal
//    ext-vector float4: 1 KB contiguous per wave instr instead of 4x64B dwords.
__global__ void __launch_bounds__(256) gemm_sig_kernel(float* __restrict__ out)
{
    const float* zf = out + (size_t)N_NODES * N_NODES;
    // 2*128*SSTR shorts = 36864 B; epilogue reuses it as fp32 sC[64][CSTR]
    // (64*132*4 = 33792 B <= 36864 B).
    __shared__ __align__(16) unsigned short sAB[2 * 128 * SSTR];
    unsigned short* sA = sAB;
    unsigned short* sB = sAB + 128 * SSTR;

    int t    = threadIdx.x;
    int lane = t & 63;
    int wave = t >> 6;
    int wm = wave >> 1, wn = wave & 1;
    int j0 = blockIdx.x * 128;            // columns fast
    int i0 = blockIdx.y * 128;            // row band
    int l15  = lane & 15;
    int quad = lane >> 4;

    // ---- stage both 128x64 fp32 panels into LDS as bf16 ----
    {
        int r  = t >> 4;                 // 0..15
        int c4 = (t & 15) << 2;          // 0..60 step 4
        #pragma unroll
        for (int pass = 0; pass < 8; ++pass) {
            int row = pass * 16 + r;
            int ga = i0 + row; if (ga >= N_NODES) ga = N_NODES - 1;
            int gb = j0 + row; if (gb >= N_NODES) gb = N_NODES - 1;
            float4 va = *(const float4*)(zf + (size_t)ga * DIM_H + c4);
            float4 vb = *(const float4*)(zf + (size_t)gb * DIM_H + c4);
            ushort4 ha, hb;
            ha.x = f2bf(va.x); ha.y = f2bf(va.y); ha.z = f2bf(va.z); ha.w = f2bf(va.w);
            hb.x = f2bf(vb.x); hb.y = f2bf(vb.y); hb.z = f2bf(vb.z); hb.w = f2bf(vb.w);
            *(ushort4*)(&sA[row * SSTR + c4]) = ha;
            *(ushort4*)(&sB[row * SSTR + c4]) = hb;
        }
    }
    __syncthreads();

    // ---- MFMA: each wave 64x64 = 4x4 frags, K=64 in two K=32 steps ----
    f32x4 acc[4][4];
    #pragma unroll
    for (int a = 0; a < 4; ++a)
        #pragma unroll
        for (int b = 0; b < 4; ++b) acc[a][b] = (f32x4)0.f;

    #pragma unroll
    for (int s = 0; s < 2; ++s) {
        int kb = quad * 8 + s * 32;               // A[m=lane&15][k=quad*8+j]
        short8 af[4], bfr[4];
        #pragma unroll
        for (int mi = 0; mi < 4; ++mi)
            af[mi] = *(const short8*)(&sA[(wm * 64 + mi * 16 + l15) * SSTR + kb]);
        #pragma unroll
        for (int ni = 0; ni < 4; ++ni)
            bfr[ni] = *(const short8*)(&sB[(wn * 64 + ni * 16 + l15) * SSTR + kb]);
        #pragma unroll
        for (int mi = 0; mi < 4; ++mi)
            #pragma unroll
            for (int ni = 0; ni < 4; ++ni)
                acc[mi][ni] = __builtin_amdgcn_mfma_f32_16x16x32_bf16(
                    af[mi], bfr[ni], acc[mi][ni], 0, 0, 0);
    }

    // ---- epilogue: LDS transpose -> sigmoid -> nontemporal float4 stores ----
    // C/D frag layout: col = lane&15, row = quad*4 + r.
    float* sC = (float*)sAB;
    #pragma unroll
    for (int half = 0; half < 2; ++half) {
        __syncthreads();   // prior LDS readers (frags / previous half) done
        if (wm == half) {
            #pragma unroll
            for (int mi = 0; mi < 4; ++mi)
                #pragma unroll
                for (int ni = 0; ni < 4; ++ni)
                    #pragma unroll
                    for (int r = 0; r < 4; ++r)
                        sC[(mi * 16 + quad * 4 + r) * CSTR + wn * 64 + ni * 16 + l15]
                            = acc[mi][ni][r];
        }
        __syncthreads();
        int i0h = i0 + half * 64;
        #pragma unroll
        for (int it = 0; it < 8; ++it) {
            int idx = it * 256 + t;           // 0..2047 over 64 rows x 32 float4
            int row = idx >> 5;
            int c4  = (idx & 31) << 2;
            f32x4 v = *(const f32x4*)&sC[row * CSTR + c4];
            f32x4 sg;
            sg.x = 1.0f / (1.0f + __expf(-v.x));
            sg.y = 1.0f / (1.0f + __expf(-v.y));
            sg.z = 1.0f / (1.0f + __expf(-v.z));
            sg.w = 1.0f / (1.0f + __expf(-v.w));
            int grow = i0h + row;
            int gcol = j0 + c4;
            if (grow < N_NODES && gcol + 3 < N_NODES) {   // N%4==0 -> float4-granular
                __builtin_nontemporal_store(
                    sg, (f32x4*)(out + (size_t)grow * N_NODES + gcol));
            }
        }
    }
}

extern "C" void kernel_launch(void* const* d_in, const int* in_sizes, int n_in,
                              void* d_out, int out_size, void* d_ws, size_t ws_size,
                              hipStream_t stream) {
    const float* x     = (const float*)d_in[0];  // [N,128] fp32
    const int*   ei    = (const int*)d_in[1];    // [2,E] int32
    const float* ew    = (const float*)d_in[2];  // [E] fp32
    const float* wrel  = (const float*)d_in[3];  // [128,64] fp32
    const float* wroot = (const float*)d_in[4];  // [128,64] fp32
    const float* bias  = (const float*)d_in[5];  // [64] fp32
    float* out = (float*)d_out;                  // fp32: adj [N*N] then z [N*64]

    // CSR scratch at the FRONT of the adj region (first ~1.4 MB of 400 MB),
    // fully overwritten by gemm_sig afterwards. d_ws unused.
    char* base = (char*)d_out;
    int* esorted = (int*)(base);                 // E ints
    int* deg     = (int*)(base + 1280000);       // N ints
    int* offs    = (int*)(base + 1320000);       // N+1 ints
    int* cursor  = (int*)(base + 1360004);       // N ints

    hipMemsetAsync(deg, 0, N_NODES * sizeof(int), stream);
    hist_kernel<<<(N_EDGES + 255) / 256, 256, 0, stream>>>(ei, deg);
    scan_kernel<<<1, 1024, 0, stream>>>(deg, offs, cursor);
    bucket_kernel<<<(N_EDGES + 255) / 256, 256, 0, stream>>>(ei, cursor, esorted);
    agg_dense_kernel<<<N_NODES, 64, 0, stream>>>(x, ei, ew, wrel, wroot, bias,
                                                 offs, esorted, out);
    dim3 grid((N_NODES + 127) / 128, (N_NODES + 127) / 128);  // x = cols, y = rows
    gemm_sig_kernel<<<grid, 256, 0, stream>>>(out);
}

// Round 4
// 517.446 us; speedup vs baseline: 1.0955x; 1.0073x over previous
//
#include <hip/hip_runtime.h>
#include <hip/hip_bf16.h>
#include <stdint.h>

// GCNAE: N nodes, E edges, IN features, H hidden.
// Inputs fp32 (bf16-rounded values). Output fp32: adj [N,N] then z [N,H].
#define N_NODES 10000
#define N_EDGES 320000
#define DIM_IN  128
#define DIM_H   64
#define SSTR    72     // LDS row stride in shorts (64 + 8 pad -> 2-way banks only)
#define CSTR    132    // fp32 epilogue LDS stride (128 + 4 pad -> 2-way banks)

typedef __attribute__((ext_vector_type(8))) short  short8;   // 8 bf16 (MFMA A/B frag)
typedef __attribute__((ext_vector_type(8))) unsigned short ushort8;
typedef __attribute__((ext_vector_type(4))) float  f32x4;    // MFMA C/D frag + stores

__device__ __forceinline__ unsigned short f2bf(float f) {
    union { float f; unsigned int i; } v; v.f = f;
    unsigned int u = v.i;
    return (unsigned short)((u + 0x7fffu + ((u >> 16) & 1u)) >> 16);  // RNE
}

// ---- 1. histogram of in-degrees -------------------------------------------
__global__ void hist_kernel(const int* __restrict__ ei, int* __restrict__ deg) {
    int e = blockIdx.x * blockDim.x + threadIdx.x;
    if (e < N_EDGES) atomicAdd(&deg[ei[N_EDGES + e]], 1);   // row 1 = dst
}

// ---- 2. exclusive scan (single block, 1024 threads, 10 elems/thread) ------
__global__ void __launch_bounds__(1024) scan_kernel(const int* __restrict__ deg,
                                                    int* __restrict__ offs,
                                                    int* __restrict__ cursor) {
    __shared__ int part[1024];
    int t = threadIdx.x;
    int base = t * 10;
    int local[10];
    int s = 0;
    for (int i = 0; i < 10; ++i) {
        int idx = base + i;
        int d = (idx < N_NODES) ? deg[idx] : 0;
        local[i] = d; s += d;
    }
    part[t] = s;
    __syncthreads();
    for (int o = 1; o < 1024; o <<= 1) {
        int add = (t >= o) ? part[t - o] : 0;
        __syncthreads();
        part[t] += add;
        __syncthreads();
    }
    int run = part[t] - s;
    for (int i = 0; i < 10; ++i) {
        int idx = base + i;
        if (idx < N_NODES) { offs[idx] = run; cursor[idx] = run; run += local[i]; }
    }
    if (t == 1023) offs[N_NODES] = part[1023];
}

// ---- 3. bucket edge ids into CSR ------------------------------------------
__global__ void bucket_kernel(const int* __restrict__ ei, int* __restrict__ cursor,
                              int* __restrict__ esorted) {
    int e = blockIdx.x * blockDim.x + threadIdx.x;
    if (e < N_EDGES) {
        int d = ei[N_EDGES + e];
        int slot = atomicAdd(&cursor[d], 1);
        esorted[slot] = e;
    }
}

// ---- 4. per-node aggregate + fused dense: z = agg@W_rel + x@W_root + b ----
// R2 rework: edge loop is 2-wide (half-wave per edge, float4 per lane) ->
// half the serial trips, 2 independent load chains, 16B/lane gathers.
// Also emits z in bf16 (to d_ws) so gemm stages without fp32 reads + cvt.
__global__ void __launch_bounds__(64) agg_dense_kernel(
    const float* __restrict__ x,
    const int* __restrict__ ei,
    const float* __restrict__ ew,
    const float* __restrict__ wrel,
    const float* __restrict__ wroot,
    const float* __restrict__ bias,
    const int* __restrict__ offs,
    const int* __restrict__ esorted,
    float* __restrict__ out,               // d_out (fp32)
    unsigned short* __restrict__ zb)       // d_ws: z in bf16 [N,64]
{
    int i = blockIdx.x;
    int lane = threadIdx.x;
    int half = lane >> 5;                  // which edge slot (0/1)
    int l32  = lane & 31;                  // feature quad id
    __shared__ float aggL[DIM_IN];
    __shared__ float xL[DIM_IN];

    int beg = offs[i], end = offs[i + 1];
    f32x4 a = (f32x4)0.f;
    for (int p = beg + half; p < end; p += 2) {
        int e = esorted[p];
        int s = ei[e];                     // row 0 = src
        float w = ew[e];
        f32x4 xv = *(const f32x4*)(x + (size_t)s * DIM_IN + l32 * 4);
        a += xv * w;
    }
    // combine the two half-wave partial sums (feature f lives in lane f/4 of
    // both halves): butterfly across lane^32.
    f32x4 b;
    b.x = __shfl_xor(a.x, 32);
    b.y = __shfl_xor(a.y, 32);
    b.z = __shfl_xor(a.z, 32);
    b.w = __shfl_xor(a.w, 32);
    a += b;
    if (half == 0) *(f32x4*)&aggL[l32 * 4] = a;

    float2 xi = ((const float2*)(x + (size_t)i * DIM_IN))[lane];
    xL[2 * lane]     = xi.x;
    xL[2 * lane + 1] = xi.y;
    __syncthreads();

    int h = lane;
    float acc = bias[h];
    for (int k = 0; k < DIM_IN; ++k) {
        acc += aggL[k] * wrel[k * DIM_H + h];
        acc += xL[k]   * wroot[k * DIM_H + h];
    }
    out[(size_t)N_NODES * N_NODES + (size_t)i * DIM_H + h] = acc;  // fp32 z
    zb[(size_t)i * DIM_H + h] = f2bf(acc);                          // bf16 z
}

// ---- 5. adj = sigmoid(z @ z^T) --------------------------------------------
// Block tile 128x128, 4 waves of 64x64. Panels staged from PRE-CONVERTED
// bf16 z (d_ws): halves read traffic (200 MB total vs 400) and removes the
// 16x f2bf chain per thread. A wave's stage load is 1 KB fully contiguous.
// Epilogue: LDS transpose -> sigmoid -> nontemporal float4 row stores.
__global__ void __launch_bounds__(256) gemm_sig_kernel(
    const unsigned short* __restrict__ zb, float* __restrict__ out)
{
    // 2*128*SSTR shorts = 36864 B; epilogue reuses it as fp32 sC[64][CSTR]
    // (64*132*4 = 33792 B <= 36864 B).
    __shared__ __align__(16) unsigned short sAB[2 * 128 * SSTR];
    unsigned short* sA = sAB;
    unsigned short* sB = sAB + 128 * SSTR;

    int t    = threadIdx.x;
    int lane = t & 63;
    int wave = t >> 6;
    int wm = wave >> 1, wn = wave & 1;
    int j0 = blockIdx.x * 128;            // columns fast
    int i0 = blockIdx.y * 128;            // row band
    int l15  = lane & 15;
    int quad = lane >> 4;

    // ---- stage both 128-row bf16 panels into LDS ----
    // panel = 128 rows x 8 ushort8 chunks (16B); 1024 chunks / 256 thr = 4 ea.
    #pragma unroll
    for (int pass = 0; pass < 4; ++pass) {
        int c   = pass * 256 + t;         // 0..1023
        int row = c >> 3;
        int c8  = (c & 7) << 3;           // ushort offset in row
        int ga = i0 + row; if (ga >= N_NODES) ga = N_NODES - 1;
        int gb = j0 + row; if (gb >= N_NODES) gb = N_NODES - 1;
        ushort8 va = *(const ushort8*)(zb + (size_t)ga * DIM_H + c8);
        ushort8 vb = *(const ushort8*)(zb + (size_t)gb * DIM_H + c8);
        *(ushort8*)(&sA[row * SSTR + c8]) = va;
        *(ushort8*)(&sB[row * SSTR + c8]) = vb;
    }
    __syncthreads();

    // ---- MFMA: each wave 64x64 = 4x4 frags, K=64 in two K=32 steps ----
    f32x4 acc[4][4];
    #pragma unroll
    for (int a = 0; a < 4; ++a)
        #pragma unroll
        for (int b = 0; b < 4; ++b) acc[a][b] = (f32x4)0.f;

    #pragma unroll
    for (int s = 0; s < 2; ++s) {
        int kb = quad * 8 + s * 32;               // A[m=lane&15][k=quad*8+j]
        short8 af[4], bfr[4];
        #pragma unroll
        for (int mi = 0; mi < 4; ++mi)
            af[mi] = *(const short8*)(&sA[(wm * 64 + mi * 16 + l15) * SSTR + kb]);
        #pragma unroll
        for (int ni = 0; ni < 4; ++ni)
            bfr[ni] = *(const short8*)(&sB[(wn * 64 + ni * 16 + l15) * SSTR + kb]);
        #pragma unroll
        for (int mi = 0; mi < 4; ++mi)
            #pragma unroll
            for (int ni = 0; ni < 4; ++ni)
                acc[mi][ni] = __builtin_amdgcn_mfma_f32_16x16x32_bf16(
                    af[mi], bfr[ni], acc[mi][ni], 0, 0, 0);
    }

    // ---- epilogue: LDS transpose -> sigmoid -> nontemporal float4 stores ----
    // C/D frag layout: col = lane&15, row = quad*4 + r.
    float* sC = (float*)sAB;
    #pragma unroll
    for (int half = 0; half < 2; ++half) {
        __syncthreads();   // prior LDS readers (frags / previous half) done
        if (wm == half) {
            #pragma unroll
            for (int mi = 0; mi < 4; ++mi)
                #pragma unroll
                for (int ni = 0; ni < 4; ++ni)
                    #pragma unroll
                    for (int r = 0; r < 4; ++r)
                        sC[(mi * 16 + quad * 4 + r) * CSTR + wn * 64 + ni * 16 + l15]
                            = acc[mi][ni][r];
        }
        __syncthreads();
        int i0h = i0 + half * 64;
        #pragma unroll
        for (int it = 0; it < 8; ++it) {
            int idx = it * 256 + t;           // 0..2047 over 64 rows x 32 float4
            int row = idx >> 5;
            int c4  = (idx & 31) << 2;
            f32x4 v = *(const f32x4*)&sC[row * CSTR + c4];
            f32x4 sg;
            sg.x = 1.0f / (1.0f + __expf(-v.x));
            sg.y = 1.0f / (1.0f + __expf(-v.y));
            sg.z = 1.0f / (1.0f + __expf(-v.z));
            sg.w = 1.0f / (1.0f + __expf(-v.w));
            int grow = i0h + row;
            int gcol = j0 + c4;
            if (grow < N_NODES && gcol + 3 < N_NODES) {   // N%4==0 -> float4-granular
                __builtin_nontemporal_store(
                    sg, (f32x4*)(out + (size_t)grow * N_NODES + gcol));
            }
        }
    }
}

extern "C" void kernel_launch(void* const* d_in, const int* in_sizes, int n_in,
                              void* d_out, int out_size, void* d_ws, size_t ws_size,
                              hipStream_t stream) {
    const float* x     = (const float*)d_in[0];  // [N,128] fp32
    const int*   ei    = (const int*)d_in[1];    // [2,E] int32
    const float* ew    = (const float*)d_in[2];  // [E] fp32
    const float* wrel  = (const float*)d_in[3];  // [128,64] fp32
    const float* wroot = (const float*)d_in[4];  // [128,64] fp32
    const float* bias  = (const float*)d_in[5];  // [64] fp32
    float* out = (float*)d_out;                  // fp32: adj [N*N] then z [N*64]

    // Scratch in d_ws (~2.7 MB; ws is ~1.2 GB per the harness poison size).
    // Everything read is fully written first (poison-safe).
    char* base = (char*)d_ws;
    unsigned short* zb = (unsigned short*)(base);       // [N,64] bf16 z
    int* esorted = (int*)(base + 1280000);              // E ints
    int* deg     = (int*)(base + 2560000);              // N ints
    int* offs    = (int*)(base + 2600000);              // N+1 ints
    int* cursor  = (int*)(base + 2640004);              // N ints

    hipMemsetAsync(deg, 0, N_NODES * sizeof(int), stream);
    hist_kernel<<<(N_EDGES + 255) / 256, 256, 0, stream>>>(ei, deg);
    scan_kernel<<<1, 1024, 0, stream>>>(deg, offs, cursor);
    bucket_kernel<<<(N_EDGES + 255) / 256, 256, 0, stream>>>(ei, cursor, esorted);
    agg_dense_kernel<<<N_NODES, 64, 0, stream>>>(x, ei, ew, wrel, wroot, bias,
                                                 offs, esorted, out, zb);
    dim3 grid((N_NODES + 127) / 128, (N_NODES + 127) / 128);  // x = cols, y = rows
    gemm_sig_kernel<<<grid, 256, 0, stream>>>(zb, out);
}

// Round 6
// 504.185 us; speedup vs baseline: 1.1243x; 1.0263x over previous
//
#include <hip/hip_runtime.h>
#include <hip/hip_bf16.h>
#include <stdint.h>

// GCNAE: N nodes, E edges, IN features, H hidden.
// Inputs fp32 (bf16-rounded values). Output fp32: adj [N,N] then z [N,H].
#define N_NODES 10000
#define N_EDGES 320000
#define DIM_IN  128
#define DIM_H   64
#define SSTR    72     // LDS row stride in shorts (64 + 8 pad -> 2-way banks only)
#define CSTR    132    // fp32 epilogue LDS stride (128 + 4 pad -> 2-way banks)

typedef __attribute__((ext_vector_type(8))) short  short8;   // 8 bf16 (MFMA A/B frag)
typedef __attribute__((ext_vector_type(8))) unsigned short ushort8;
typedef __attribute__((ext_vector_type(4))) float  f32x4;    // MFMA C/D frag + stores

__device__ __forceinline__ unsigned short f2bf(float f) {
    union { float f; unsigned int i; } v; v.f = f;
    unsigned int u = v.i;
    return (unsigned short)((u + 0x7fffu + ((u >> 16) & 1u)) >> 16);  // RNE
}

// ---- 1. histogram of in-degrees -------------------------------------------
__global__ void hist_kernel(const int* __restrict__ ei, int* __restrict__ deg) {
    int e = blockIdx.x * blockDim.x + threadIdx.x;
    if (e < N_EDGES) atomicAdd(&deg[ei[N_EDGES + e]], 1);   // row 1 = dst
}

// ---- 2. exclusive scan (single block, 1024 threads, 10 elems/thread) ------
__global__ void __launch_bounds__(1024) scan_kernel(const int* __restrict__ deg,
                                                    int* __restrict__ offs,
                                                    int* __restrict__ cursor) {
    __shared__ int part[1024];
    int t = threadIdx.x;
    int base = t * 10;
    int local[10];
    int s = 0;
    for (int i = 0; i < 10; ++i) {
        int idx = base + i;
        int d = (idx < N_NODES) ? deg[idx] : 0;
        local[i] = d; s += d;
    }
    part[t] = s;
    __syncthreads();
    for (int o = 1; o < 1024; o <<= 1) {
        int add = (t >= o) ? part[t - o] : 0;
        __syncthreads();
        part[t] += add;
        __syncthreads();
    }
    int run = part[t] - s;
    for (int i = 0; i < 10; ++i) {
        int idx = base + i;
        if (idx < N_NODES) { offs[idx] = run; cursor[idx] = run; run += local[i]; }
    }
    if (t == 1023) offs[N_NODES] = part[1023];
}

// ---- 3. bucket edges into CSR with PACKED payload -------------------------
// R4: write {src, w_bits} int2 at the slot instead of the edge id. This
// removes the esorted->ei/ew indirection from the agg inner loop: its chain
// becomes {sequential 8B stream load -> x gather}, fully pipelineable.
__global__ void bucket_kernel(const int* __restrict__ ei,
                              const float* __restrict__ ew,
                              int* __restrict__ cursor,
                              int2* __restrict__ swsrt) {
    int e = blockIdx.x * blockDim.x + threadIdx.x;
    if (e < N_EDGES) {
        int d = ei[N_EDGES + e];
        int slot = atomicAdd(&cursor[d], 1);
        int2 pay;
        pay.x = ei[e];                       // src
        pay.y = __float_as_int(ew[e]);       // weight bits
        swsrt[slot] = pay;
    }
}

// ---- 4. per-node aggregate + fused dense: z = agg@W_rel + x@W_root + b ----
// Edge loop 2-wide (half-wave per edge, f32x4 per lane). Packed CSR payload
// kills the per-edge indirection; unroll-4 keeps ~8 gathers in flight/wave.
// Emits z in bf16 (to d_ws) so gemm stages without fp32 reads + cvt.
__global__ void __launch_bounds__(64) agg_dense_kernel(
    const float* __restrict__ x,
    const int2* __restrict__ swsrt,
    const float* __restrict__ wrel,
    const float* __restrict__ wroot,
    const float* __restrict__ bias,
    const int* __restrict__ offs,
    float* __restrict__ out,               // d_out (fp32)
    unsigned short* __restrict__ zb)       // d_ws: z in bf16 [N,64]
{
    int i = blockIdx.x;
    int lane = threadIdx.x;
    int half = lane >> 5;                  // which edge slot (0/1)
    int l32  = lane & 31;                  // feature quad id
    __shared__ float aggL[DIM_IN];
    __shared__ float xL[DIM_IN];

    int beg = offs[i], end = offs[i + 1];
    f32x4 a = (f32x4)0.f;
    #pragma unroll 4
    for (int p = beg + half; p < end; p += 2) {
        int2 sw = swsrt[p];
        float w = __int_as_float(sw.y);
        f32x4 xv = *(const f32x4*)(x + (size_t)sw.x * DIM_IN + l32 * 4);
        a += xv * w;
    }
    // combine the two half-wave partial sums (feature f lives in lane f/4 of
    // both halves): butterfly across lane^32.
    f32x4 b;
    b.x = __shfl_xor(a.x, 32);
    b.y = __shfl_xor(a.y, 32);
    b.z = __shfl_xor(a.z, 32);
    b.w = __shfl_xor(a.w, 32);
    a += b;
    if (half == 0) *(f32x4*)&aggL[l32 * 4] = a;

    float2 xi = ((const float2*)(x + (size_t)i * DIM_IN))[lane];
    xL[2 * lane]     = xi.x;
    xL[2 * lane + 1] = xi.y;
    __syncthreads();

    int h = lane;
    float acc = bias[h];
    for (int k = 0; k < DIM_IN; ++k) {
        acc += aggL[k] * wrel[k * DIM_H + h];
        acc += xL[k]   * wroot[k * DIM_H + h];
    }
    out[(size_t)N_NODES * N_NODES + (size_t)i * DIM_H + h] = acc;  // fp32 z
    zb[(size_t)i * DIM_H + h] = f2bf(acc);                          // bf16 z
}

// ---- 5. adj = sigmoid(z @ z^T) --------------------------------------------
// Block tile 128x128, 4 waves of 64x64. Panels staged from PRE-CONVERTED
// bf16 z (d_ws). Epilogue: LDS transpose -> sigmoid -> nontemporal float4.
__global__ void __launch_bounds__(256) gemm_sig_kernel(
    const unsigned short* __restrict__ zb, float* __restrict__ out)
{
    // 2*128*SSTR shorts = 36864 B; epilogue reuses it as fp32 sC[64][CSTR]
    // (64*132*4 = 33792 B <= 36864 B).
    __shared__ __align__(16) unsigned short sAB[2 * 128 * SSTR];
    unsigned short* sA = sAB;
    unsigned short* sB = sAB + 128 * SSTR;

    int t    = threadIdx.x;
    int lane = t & 63;
    int wave = t >> 6;
    int wm = wave >> 1, wn = wave & 1;
    int j0 = blockIdx.x * 128;            // columns fast
    int i0 = blockIdx.y * 128;            // row band
    int l15  = lane & 15;
    int quad = lane >> 4;

    // ---- stage both 128-row bf16 panels into LDS ----
    // panel = 128 rows x 8 ushort8 chunks (16B); 1024 chunks / 256 thr = 4 ea.
    #pragma unroll
    for (int pass = 0; pass < 4; ++pass) {
        int c   = pass * 256 + t;         // 0..1023
        int row = c >> 3;
        int c8  = (c & 7) << 3;           // ushort offset in row
        int ga = i0 + row; if (ga >= N_NODES) ga = N_NODES - 1;
        int gb = j0 + row; if (gb >= N_NODES) gb = N_NODES - 1;
        ushort8 va = *(const ushort8*)(zb + (size_t)ga * DIM_H + c8);
        ushort8 vb = *(const ushort8*)(zb + (size_t)gb * DIM_H + c8);
        *(ushort8*)(&sA[row * SSTR + c8]) = va;
        *(ushort8*)(&sB[row * SSTR + c8]) = vb;
    }
    __syncthreads();

    // ---- MFMA: each wave 64x64 = 4x4 frags, K=64 in two K=32 steps ----
    f32x4 acc[4][4];
    #pragma unroll
    for (int a = 0; a < 4; ++a)
        #pragma unroll
        for (int b = 0; b < 4; ++b) acc[a][b] = (f32x4)0.f;

    #pragma unroll
    for (int s = 0; s < 2; ++s) {
        int kb = quad * 8 + s * 32;               // A[m=lane&15][k=quad*8+j]
        short8 af[4], bfr[4];
        #pragma unroll
        for (int mi = 0; mi < 4; ++mi)
            af[mi] = *(const short8*)(&sA[(wm * 64 + mi * 16 + l15) * SSTR + kb]);
        #pragma unroll
        for (int ni = 0; ni < 4; ++ni)
            bfr[ni] = *(const short8*)(&sB[(wn * 64 + ni * 16 + l15) * SSTR + kb]);
        #pragma unroll
        for (int mi = 0; mi < 4; ++mi)
            #pragma unroll
            for (int ni = 0; ni < 4; ++ni)
                acc[mi][ni] = __builtin_amdgcn_mfma_f32_16x16x32_bf16(
                    af[mi], bfr[ni], acc[mi][ni], 0, 0, 0);
    }

    // ---- epilogue: LDS transpose -> sigmoid -> nontemporal float4 stores ----
    // C/D frag layout: col = lane&15, row = quad*4 + r.
    float* sC = (float*)sAB;
    #pragma unroll
    for (int half = 0; half < 2; ++half) {
        __syncthreads();   // prior LDS readers (frags / previous half) done
        if (wm == half) {
            #pragma unroll
            for (int mi = 0; mi < 4; ++mi)
                #pragma unroll
                for (int ni = 0; ni < 4; ++ni)
                    #pragma unroll
                    for (int r = 0; r < 4; ++r)
                        sC[(mi * 16 + quad * 4 + r) * CSTR + wn * 64 + ni * 16 + l15]
                            = acc[mi][ni][r];
        }
        __syncthreads();
        int i0h = i0 + half * 64;
        #pragma unroll
        for (int it = 0; it < 8; ++it) {
            int idx = it * 256 + t;           // 0..2047 over 64 rows x 32 float4
            int row = idx >> 5;
            int c4  = (idx & 31) << 2;
            f32x4 v = *(const f32x4*)&sC[row * CSTR + c4];
            f32x4 sg;
            sg.x = 1.0f / (1.0f + __expf(-v.x));
            sg.y = 1.0f / (1.0f + __expf(-v.y));
            sg.z = 1.0f / (1.0f + __expf(-v.z));
            sg.w = 1.0f / (1.0f + __expf(-v.w));
            int grow = i0h + row;
            int gcol = j0 + c4;
            if (grow < N_NODES && gcol + 3 < N_NODES) {   // N%4==0 -> float4-granular
                __builtin_nontemporal_store(
                    sg, (f32x4*)(out + (size_t)grow * N_NODES + gcol));
            }
        }
    }
}

extern "C" void kernel_launch(void* const* d_in, const int* in_sizes, int n_in,
                              void* d_out, int out_size, void* d_ws, size_t ws_size,
                              hipStream_t stream) {
    const float* x     = (const float*)d_in[0];  // [N,128] fp32
    const int*   ei    = (const int*)d_in[1];    // [2,E] int32
    const float* ew    = (const float*)d_in[2];  // [E] fp32
    const float* wrel  = (const float*)d_in[3];  // [128,64] fp32
    const float* wroot = (const float*)d_in[4];  // [128,64] fp32
    const float* bias  = (const float*)d_in[5];  // [64] fp32
    float* out = (float*)d_out;                  // fp32: adj [N*N] then z [N*64]

    // Scratch in d_ws (~4 MB of ~1.2 GB). Everything read is written first.
    char* base = (char*)d_ws;
    unsigned short* zb = (unsigned short*)(base);       // [N,64] bf16 z (1.28 MB)
    int2* swsrt  = (int2*)(base + 1280000);             // E int2 packed {src,w}
    int* deg     = (int*)(base + 3840000);              // N ints
    int* offs    = (int*)(base + 3880000);              // N+1 ints
    int* cursor  = (int*)(base + 3920004);              // N ints

    hipMemsetAsync(deg, 0, N_NODES * sizeof(int), stream);
    hist_kernel<<<(N_EDGES + 255) / 256, 256, 0, stream>>>(ei, deg);
    scan_kernel<<<1, 1024, 0, stream>>>(deg, offs, cursor);
    bucket_kernel<<<(N_EDGES + 255) / 256, 256, 0, stream>>>(ei, ew, cursor, swsrt);
    agg_dense_kernel<<<N_NODES, 64, 0, stream>>>(x, swsrt, wrel, wroot, bias,
                                                 offs, out, zb);
    dim3 grid((N_NODES + 127) / 128, (N_NODES + 127) / 128);  // x = cols, y = rows
    gemm_sig_kernel<<<grid, 256, 0, stream>>>(zb, out);
}

// Round 7
// 499.603 us; speedup vs baseline: 1.1346x; 1.0092x over previous
//
#include <hip/hip_runtime.h>
#include <hip/hip_bf16.h>
#include <stdint.h>

// GCNAE: N nodes, E edges, IN features, H hidden.
// Inputs fp32 (bf16-rounded values). Output fp32: adj [N,N] then z [N,H].
#define N_NODES 10000
#define N_EDGES 320000
#define DIM_IN  128
#define DIM_H   64
#define SSTR    72     // LDS row stride in shorts (64 + 8 pad -> 2-way banks only)
#define CSTR    132    // fp32 epilogue LDS stride (128 + 4 pad -> 2-way banks)

typedef __attribute__((ext_vector_type(8))) short  short8;   // 8 bf16 (MFMA A/B frag)
typedef __attribute__((ext_vector_type(8))) unsigned short ushort8;
typedef __attribute__((ext_vector_type(4))) float  f32x4;    // MFMA C/D frag + stores

__device__ __forceinline__ unsigned short f2bf(float f) {
    union { float f; unsigned int i; } v; v.f = f;
    unsigned int u = v.i;
    return (unsigned short)((u + 0x7fffu + ((u >> 16) & 1u)) >> 16);  // RNE
}

// ---- 1. histogram of in-degrees -------------------------------------------
__global__ void hist_kernel(const int* __restrict__ ei, int* __restrict__ deg) {
    int e = blockIdx.x * blockDim.x + threadIdx.x;
    if (e < N_EDGES) atomicAdd(&deg[ei[N_EDGES + e]], 1);   // row 1 = dst
}

// ---- 2. exclusive scan (single block, 1024 threads, 10 elems/thread) ------
__global__ void __launch_bounds__(1024) scan_kernel(const int* __restrict__ deg,
                                                    int* __restrict__ offs,
                                                    int* __restrict__ cursor) {
    __shared__ int part[1024];
    int t = threadIdx.x;
    int base = t * 10;
    int local[10];
    int s = 0;
    for (int i = 0; i < 10; ++i) {
        int idx = base + i;
        int d = (idx < N_NODES) ? deg[idx] : 0;
        local[i] = d; s += d;
    }
    part[t] = s;
    __syncthreads();
    for (int o = 1; o < 1024; o <<= 1) {
        int add = (t >= o) ? part[t - o] : 0;
        __syncthreads();
        part[t] += add;
        __syncthreads();
    }
    int run = part[t] - s;
    for (int i = 0; i < 10; ++i) {
        int idx = base + i;
        if (idx < N_NODES) { offs[idx] = run; cursor[idx] = run; run += local[i]; }
    }
    if (t == 1023) offs[N_NODES] = part[1023];
}

// ---- 3. bucket edges into CSR with PACKED payload -------------------------
__global__ void bucket_kernel(const int* __restrict__ ei,
                              const float* __restrict__ ew,
                              int* __restrict__ cursor,
                              int2* __restrict__ swsrt) {
    int e = blockIdx.x * blockDim.x + threadIdx.x;
    if (e < N_EDGES) {
        int d = ei[N_EDGES + e];
        int slot = atomicAdd(&cursor[d], 1);
        int2 pay;
        pay.x = ei[e];                       // src
        pay.y = __float_as_int(ew[e]);       // weight bits
        swsrt[slot] = pay;
    }
}

// ---- 4a. feature precompute: xr = x@W_rel, xw = x@W_root + b --------------
// R6 reassociation: agg@W_rel == A_w@(x@W_rel). Aggregating the 64-wide xr
// halves gather bytes and removes the dense pass from the agg kernel.
__global__ void __launch_bounds__(64) feat_kernel(
    const float* __restrict__ x,
    const float* __restrict__ wrel,
    const float* __restrict__ wroot,
    const float* __restrict__ bias,
    float* __restrict__ xr,                // [N,64] fp32
    float* __restrict__ xw)                // [N,64] fp32 (bias folded)
{
    int i = blockIdx.x;
    int lane = threadIdx.x;
    __shared__ float xL[DIM_IN];
    float2 xi = ((const float2*)(x + (size_t)i * DIM_IN))[lane];
    xL[2 * lane]     = xi.x;
    xL[2 * lane + 1] = xi.y;
    __syncthreads();

    float ar = 0.f, aw = bias[lane];
    for (int k = 0; k < DIM_IN; ++k) {
        float xv = xL[k];
        ar += xv * wrel[k * DIM_H + lane];
        aw += xv * wroot[k * DIM_H + lane];
    }
    xr[(size_t)i * DIM_H + lane] = ar;
    xw[(size_t)i * DIM_H + lane] = aw;
}

// ---- 4b. per-node aggregate: z_i = sum_j w_ji*xr_j + xw_i -----------------
// Edge loop 4-wide (quarter-wave per edge, f32x4 per lane over 64 features):
// 256B gathers, 8 serial trips at avg degree 32, unroll-4 keeps ~16 gathers
// in flight per wave. Emits z fp32 (output) + bf16 (gemm staging).
__global__ void __launch_bounds__(64) agg_kernel(
    const float* __restrict__ xr,
    const float* __restrict__ xw,
    const int2* __restrict__ swsrt,
    const int* __restrict__ offs,
    float* __restrict__ out,               // d_out (fp32 z at N*N)
    unsigned short* __restrict__ zb)       // d_ws: z in bf16 [N,64]
{
    int i = blockIdx.x;
    int lane = threadIdx.x;
    int q   = lane >> 4;                   // edge slot 0..3
    int l16 = lane & 15;                   // feature quad id (16*4 = 64 feats)

    int beg = offs[i], end = offs[i + 1];
    f32x4 a = (f32x4)0.f;
    #pragma unroll 4
    for (int p = beg + q; p < end; p += 4) {
        int2 sw = swsrt[p];
        float w = __int_as_float(sw.y);
        f32x4 v = *(const f32x4*)(xr + (size_t)sw.x * DIM_H + l16 * 4);
        a += v * w;
    }
    // combine the 4 quarter-wave partials: butterfly over lane^16, lane^32.
    f32x4 b;
    b.x = __shfl_xor(a.x, 16); b.y = __shfl_xor(a.y, 16);
    b.z = __shfl_xor(a.z, 16); b.w = __shfl_xor(a.w, 16);
    a += b;
    b.x = __shfl_xor(a.x, 32); b.y = __shfl_xor(a.y, 32);
    b.z = __shfl_xor(a.z, 32); b.w = __shfl_xor(a.w, 32);
    a += b;

    if (q == 0) {
        f32x4 w4 = *(const f32x4*)(xw + (size_t)i * DIM_H + l16 * 4);
        f32x4 z4 = a + w4;
        *(f32x4*)(out + (size_t)N_NODES * N_NODES + (size_t)i * DIM_H + l16 * 4) = z4;
        ushort4 h;
        h.x = f2bf(z4.x); h.y = f2bf(z4.y); h.z = f2bf(z4.z); h.w = f2bf(z4.w);
        *(ushort4*)(zb + (size_t)i * DIM_H + l16 * 4) = h;
    }
}

// ---- 5. adj = sigmoid(z @ z^T) --------------------------------------------
// Block tile 128x128, 4 waves of 64x64. Panels staged from PRE-CONVERTED
// bf16 z (d_ws). Epilogue: LDS transpose -> sigmoid -> nontemporal float4.
__global__ void __launch_bounds__(256) gemm_sig_kernel(
    const unsigned short* __restrict__ zb, float* __restrict__ out)
{
    // 2*128*SSTR shorts = 36864 B; epilogue reuses it as fp32 sC[64][CSTR]
    // (64*132*4 = 33792 B <= 36864 B).
    __shared__ __align__(16) unsigned short sAB[2 * 128 * SSTR];
    unsigned short* sA = sAB;
    unsigned short* sB = sAB + 128 * SSTR;

    int t    = threadIdx.x;
    int lane = t & 63;
    int wave = t >> 6;
    int wm = wave >> 1, wn = wave & 1;
    int j0 = blockIdx.x * 128;            // columns fast
    int i0 = blockIdx.y * 128;            // row band
    int l15  = lane & 15;
    int quad = lane >> 4;

    // ---- stage both 128-row bf16 panels into LDS ----
    // panel = 128 rows x 8 ushort8 chunks (16B); 1024 chunks / 256 thr = 4 ea.
    #pragma unroll
    for (int pass = 0; pass < 4; ++pass) {
        int c   = pass * 256 + t;         // 0..1023
        int row = c >> 3;
        int c8  = (c & 7) << 3;           // ushort offset in row
        int ga = i0 + row; if (ga >= N_NODES) ga = N_NODES - 1;
        int gb = j0 + row; if (gb >= N_NODES) gb = N_NODES - 1;
        ushort8 va = *(const ushort8*)(zb + (size_t)ga * DIM_H + c8);
        ushort8 vb = *(const ushort8*)(zb + (size_t)gb * DIM_H + c8);
        *(ushort8*)(&sA[row * SSTR + c8]) = va;
        *(ushort8*)(&sB[row * SSTR + c8]) = vb;
    }
    __syncthreads();

    // ---- MFMA: each wave 64x64 = 4x4 frags, K=64 in two K=32 steps ----
    f32x4 acc[4][4];
    #pragma unroll
    for (int a = 0; a < 4; ++a)
        #pragma unroll
        for (int b = 0; b < 4; ++b) acc[a][b] = (f32x4)0.f;

    #pragma unroll
    for (int s = 0; s < 2; ++s) {
        int kb = quad * 8 + s * 32;               // A[m=lane&15][k=quad*8+j]
        short8 af[4], bfr[4];
        #pragma unroll
        for (int mi = 0; mi < 4; ++mi)
            af[mi] = *(const short8*)(&sA[(wm * 64 + mi * 16 + l15) * SSTR + kb]);
        #pragma unroll
        for (int ni = 0; ni < 4; ++ni)
            bfr[ni] = *(const short8*)(&sB[(wn * 64 + ni * 16 + l15) * SSTR + kb]);
        #pragma unroll
        for (int mi = 0; mi < 4; ++mi)
            #pragma unroll
            for (int ni = 0; ni < 4; ++ni)
                acc[mi][ni] = __builtin_amdgcn_mfma_f32_16x16x32_bf16(
                    af[mi], bfr[ni], acc[mi][ni], 0, 0, 0);
    }

    // ---- epilogue: LDS transpose -> sigmoid -> nontemporal float4 stores ----
    // C/D frag layout: col = lane&15, row = quad*4 + r.
    float* sC = (float*)sAB;
    #pragma unroll
    for (int half = 0; half < 2; ++half) {
        __syncthreads();   // prior LDS readers (frags / previous half) done
        if (wm == half) {
            #pragma unroll
            for (int mi = 0; mi < 4; ++mi)
                #pragma unroll
                for (int ni = 0; ni < 4; ++ni)
                    #pragma unroll
                    for (int r = 0; r < 4; ++r)
                        sC[(mi * 16 + quad * 4 + r) * CSTR + wn * 64 + ni * 16 + l15]
                            = acc[mi][ni][r];
        }
        __syncthreads();
        int i0h = i0 + half * 64;
        #pragma unroll
        for (int it = 0; it < 8; ++it) {
            int idx = it * 256 + t;           // 0..2047 over 64 rows x 32 float4
            int row = idx >> 5;
            int c4  = (idx & 31) << 2;
            f32x4 v = *(const f32x4*)&sC[row * CSTR + c4];
            f32x4 sg;
            sg.x = 1.0f / (1.0f + __expf(-v.x));
            sg.y = 1.0f / (1.0f + __expf(-v.y));
            sg.z = 1.0f / (1.0f + __expf(-v.z));
            sg.w = 1.0f / (1.0f + __expf(-v.w));
            int grow = i0h + row;
            int gcol = j0 + c4;
            if (grow < N_NODES && gcol + 3 < N_NODES) {   // N%4==0 -> float4-granular
                __builtin_nontemporal_store(
                    sg, (f32x4*)(out + (size_t)grow * N_NODES + gcol));
            }
        }
    }
}

extern "C" void kernel_launch(void* const* d_in, const int* in_sizes, int n_in,
                              void* d_out, int out_size, void* d_ws, size_t ws_size,
                              hipStream_t stream) {
    const float* x     = (const float*)d_in[0];  // [N,128] fp32
    const int*   ei    = (const int*)d_in[1];    // [2,E] int32
    const float* ew    = (const float*)d_in[2];  // [E] fp32
    const float* wrel  = (const float*)d_in[3];  // [128,64] fp32
    const float* wroot = (const float*)d_in[4];  // [128,64] fp32
    const float* bias  = (const float*)d_in[5];  // [64] fp32
    float* out = (float*)d_out;                  // fp32: adj [N*N] then z [N*64]

    // Scratch in d_ws (~9.1 MB of ~1.2 GB). Everything read is written first.
    char* base = (char*)d_ws;
    unsigned short* zb = (unsigned short*)(base);       // [N,64] bf16 z (1.28 MB)
    float* xr    = (float*)(base + 1280000);            // [N,64] f32 x@W_rel
    float* xw    = (float*)(base + 3840000);            // [N,64] f32 x@W_root + b
    int2* swsrt  = (int2*)(base + 6400000);             // E int2 packed {src,w}
    int* deg     = (int*)(base + 8960000);              // N ints
    int* offs    = (int*)(base + 9000000);              // N+1 ints
    int* cursor  = (int*)(base + 9040004);              // N ints

    hipMemsetAsync(deg, 0, N_NODES * sizeof(int), stream);
    hist_kernel<<<(N_EDGES + 255) / 256, 256, 0, stream>>>(ei, deg);
    scan_kernel<<<1, 1024, 0, stream>>>(deg, offs, cursor);
    bucket_kernel<<<(N_EDGES + 255) / 256, 256, 0, stream>>>(ei, ew, cursor, swsrt);
    feat_kernel<<<N_NODES, 64, 0, stream>>>(x, wrel, wroot, bias, xr, xw);
    agg_kernel<<<N_NODES, 64, 0, stream>>>(xr, xw, swsrt, offs, out, zb);
    dim3 grid((N_NODES + 127) / 128, (N_NODES + 127) / 128);  // x = cols, y = rows
    gemm_sig_kernel<<<grid, 256, 0, stream>>>(zb, out);
}